// Round 1
// baseline (29.897 us; speedup 1.0000x reference)
//
#include <hip/hip_runtime.h>
#include <float.h>

// Problem constants (B=32, Cin=512, Cout=512, L=16, G=1)
constexpr int Bn   = 32;
constexpr int Cin  = 512;
constexpr int Cout = 512;
constexpr int Ln   = 16;

constexpr int KC  = 128;  // K-chunk staged in LDS
constexpr int KCP = 132;  // padded leading dim (132 % 32 == 4 -> max 2-way conflicts, free)
constexpr int NT  = 32;   // co tile per block
constexpr int RN  = 2;    // co's per thread

__global__ __launch_bounds__(256, 2) void normdist_kernel(
    const float* __restrict__ x, const float* __restrict__ lo,
    const float* __restrict__ up, const float* __restrict__ W,
    const float* __restrict__ bias, float* __restrict__ out)
{
    // x/lo/up tiles transposed to [l][ci]; W tile natural [co][ci]
    __shared__ float sX[Ln][KCP];
    __shared__ float sL[Ln][KCP];
    __shared__ float sU[Ln][KCP];
    __shared__ float sW[NT][KCP];

    const int tid = threadIdx.x;
    const int b   = blockIdx.x;        // one batch element per block (M-tile = 16 = L)
    const int n0  = blockIdx.y * NT;   // co tile base

    const int l   = tid & 15;          // this thread's l
    const int ng  = tid >> 4;          // [0,16): co-group
    const int coL = ng * RN;           // local co base in tile

    float a0[RN], a1[RN], a2[RN];
    #pragma unroll
    for (int n = 0; n < RN; ++n) { a0[n] = 0.0f; a1[n] = 0.0f; a2[n] = -FLT_MAX; }
    // a0 (out) >= 0 always; a1 (out_lo) has the max(...,0) clamp built into init.

    const float* xb = x  + b * (Cin * Ln);
    const float* lb = lo + b * (Cin * Ln);
    const float* ub = up + b * (Cin * Ln);

    for (int k0 = 0; k0 < Cin; k0 += KC) {
        // ---- stage x/lo/up: KC*16 floats each, contiguous in global.
        // thread r-th float4 covers (ci = fi>>4, l0 = fi&15 .. +3); transpose-write to [l][ci].
        #pragma unroll
        for (int r = 0; r < (KC * Ln) / (256 * 4); ++r) {
            const int f4 = tid + r * 256;
            const int fi = f4 * 4;
            const int ci = fi >> 4;
            const int l0 = fi & 15;
            const float4 vx = *reinterpret_cast<const float4*>(xb + k0 * Ln + fi);
            const float4 vl = *reinterpret_cast<const float4*>(lb + k0 * Ln + fi);
            const float4 vu = *reinterpret_cast<const float4*>(ub + k0 * Ln + fi);
            sX[l0 + 0][ci] = vx.x; sX[l0 + 1][ci] = vx.y; sX[l0 + 2][ci] = vx.z; sX[l0 + 3][ci] = vx.w;
            sL[l0 + 0][ci] = vl.x; sL[l0 + 1][ci] = vl.y; sL[l0 + 2][ci] = vl.z; sL[l0 + 3][ci] = vl.w;
            sU[l0 + 0][ci] = vu.x; sU[l0 + 1][ci] = vu.y; sU[l0 + 2][ci] = vu.z; sU[l0 + 3][ci] = vu.w;
        }
        // ---- stage W: NT x KC floats; rows contiguous in global, kept [co][ci].
        #pragma unroll
        for (int r = 0; r < (NT * KC) / (256 * 4); ++r) {
            const int f4 = tid + r * 256;
            const int fi = f4 * 4;
            const int co = fi >> 7;          // fi / KC
            const int ci = fi & (KC - 1);
            const float4 w = *reinterpret_cast<const float4*>(W + (n0 + co) * Cin + k0 + ci);
            *reinterpret_cast<float4*>(&sW[co][ci]) = w;
        }
        __syncthreads();

        // ---- compute: vectorized over 4 ci per step
        #pragma unroll 4
        for (int kk = 0; kk < KC; kk += 4) {
            const float4 vx = *reinterpret_cast<const float4*>(&sX[l][kk]);
            const float4 vl = *reinterpret_cast<const float4*>(&sL[l][kk]);
            const float4 vu = *reinterpret_cast<const float4*>(&sU[l][kk]);
            #pragma unroll
            for (int n = 0; n < RN; ++n) {
                const float4 w = *reinterpret_cast<const float4*>(&sW[coL + n][kk]);
                {
                    const float d  = vx.x - w.x;
                    const float s1 = vu.x - w.x;
                    const float s2 = vl.x - w.x;
                    a0[n] = fmaxf(a0[n], fmaxf(d,  -d ));   // v_max3
                    a2[n] = fmaxf(a2[n], fmaxf(s1, -s2));
                    a1[n] = fmaxf(a1[n], fmaxf(s2, -s1));
                }
                {
                    const float d  = vx.y - w.y;
                    const float s1 = vu.y - w.y;
                    const float s2 = vl.y - w.y;
                    a0[n] = fmaxf(a0[n], fmaxf(d,  -d ));
                    a2[n] = fmaxf(a2[n], fmaxf(s1, -s2));
                    a1[n] = fmaxf(a1[n], fmaxf(s2, -s1));
                }
                {
                    const float d  = vx.z - w.z;
                    const float s1 = vu.z - w.z;
                    const float s2 = vl.z - w.z;
                    a0[n] = fmaxf(a0[n], fmaxf(d,  -d ));
                    a2[n] = fmaxf(a2[n], fmaxf(s1, -s2));
                    a1[n] = fmaxf(a1[n], fmaxf(s2, -s1));
                }
                {
                    const float d  = vx.w - w.w;
                    const float s1 = vu.w - w.w;
                    const float s2 = vl.w - w.w;
                    a0[n] = fmaxf(a0[n], fmaxf(d,  -d ));
                    a2[n] = fmaxf(a2[n], fmaxf(s1, -s2));
                    a1[n] = fmaxf(a1[n], fmaxf(s2, -s1));
                }
            }
        }
        __syncthreads();
    }

    // ---- epilogue: out layout is 3 arrays of (B, Cout, L) concatenated
    constexpr int ONE = Bn * Cout * Ln;  // 262144
    #pragma unroll
    for (int n = 0; n < RN; ++n) {
        const int co   = n0 + coL + n;
        const float bb = bias[co];
        const int base = b * (Cout * Ln) + co * Ln + l;
        out[base]           = a0[n] + bb;
        out[ONE + base]     = a1[n] + bb;
        out[2 * ONE + base] = a2[n] + bb;
    }
}

extern "C" void kernel_launch(void* const* d_in, const int* in_sizes, int n_in,
                              void* d_out, int out_size, void* d_ws, size_t ws_size,
                              hipStream_t stream) {
    const float* x    = (const float*)d_in[0];
    const float* lo   = (const float*)d_in[1];
    const float* up   = (const float*)d_in[2];
    const float* W    = (const float*)d_in[3];
    const float* bias = (const float*)d_in[4];
    float* out        = (float*)d_out;

    dim3 grid(Bn, Cout / NT, 1);   // 32 x 16 = 512 blocks, 2/CU
    normdist_kernel<<<grid, 256, 0, stream>>>(x, lo, up, W, bias, out);
}